// Round 10
// baseline (544.076 us; speedup 1.0000x reference)
//
#include <hip/hip_runtime.h>
#include <cstdint>
#include <cstddef>

#define N_NODES 10000
#define N_EDGES 160000
#define DIM_IN  512
#define HIDDIM  128
#define NHEAD   8
#define NLAYER  4

typedef unsigned int   uint32;
typedef unsigned short ushort16;
typedef __attribute__((ext_vector_type(8))) short bf16x8;
typedef __attribute__((ext_vector_type(4))) float f32x4;

static __device__ __forceinline__ float eluf(float v)  { return v > 0.f ? v : expm1f(v); }
static __device__ __forceinline__ float lrelu(float v) { return v >= 0.f ? v : 0.2f * v; }
static __device__ __forceinline__ ushort16 f2bf(float f) {  // RNE fp32->bf16
    uint32 u = __float_as_uint(f);
    u += 0x7fffu + ((u >> 16) & 1u);
    return (ushort16)(u >> 16);
}
static __device__ __forceinline__ float blo(uint32 u) { return __uint_as_float(u << 16); }
static __device__ __forceinline__ float bhi(uint32 u) { return __uint_as_float(u & 0xffff0000u); }

#define BN_INV 0.9999950000374997f  /* 1/sqrt(1+1e-5) */

// ---------------------------------------------------------------------------
// CSR build
// ---------------------------------------------------------------------------
__global__ void k_deg(const int* __restrict__ ei, int* __restrict__ deg) {
    int t = blockIdx.x * 256 + threadIdx.x;
    if (t < N_EDGES) atomicAdd(&deg[ei[N_EDGES + t]], 1);
}

__global__ __launch_bounds__(1024) void k_scan(const int* __restrict__ deg,
                                               int* __restrict__ rowptr,
                                               int* __restrict__ cursor) {
    __shared__ int sd[1024];
    __shared__ int carry;
    int tid = threadIdx.x;
    if (tid == 0) { carry = 0; rowptr[0] = 0; }
    __syncthreads();
    for (int base = 0; base < N_NODES; base += 1024) {
        int i = base + tid;
        int v = (i < N_NODES) ? (deg[i] + 1) : 0;  // +1 = self loop
        sd[tid] = v;
        __syncthreads();
        for (int ofs = 1; ofs < 1024; ofs <<= 1) {
            int t = (tid >= ofs) ? sd[tid - ofs] : 0;
            __syncthreads();
            sd[tid] += t;
            __syncthreads();
        }
        int inc = sd[tid] + carry;
        if (i < N_NODES) { rowptr[i + 1] = inc; cursor[i] = inc - v; }
        __syncthreads();
        if (tid == 1023) carry = inc;
        __syncthreads();
    }
}

__global__ void k_scatter(const int* __restrict__ ei, int* __restrict__ cursor,
                          int* __restrict__ csr) {
    int t = blockIdx.x * 256 + threadIdx.x;
    if (t < N_EDGES) {
        int s = ei[t];
        int d = ei[N_EDGES + t];
        int p = atomicAdd(&cursor[d], 1);
        csr[p] = s;
    } else if (t < N_EDGES + N_NODES) {
        int n = t - N_EDGES;
        int p = atomicAdd(&cursor[n], 1);
        csr[p] = n;  // self loop
    }
}

// ---------------------------------------------------------------------------
// bf16-MFMA GEMM, BM=BN=64, 4 waves. ALPHA=1: fused alpha_s/alpha_d partial
// dots from the fp32 accumulators (block spans half a head; 64|128), reduced
// across the 16-lane col groups and atomicAdd'ed into as_/ad_ (zeroed before).
// XOR swizzle byte^=(row&7)<<4 -> conflict-free stride-256B fragment reads.
// ---------------------------------------------------------------------------
template <int ACT, int OUTBF, int ALPHA>
__global__ __launch_bounds__(256) void k_gemm_mfma(const float* __restrict__ A,
                                                   const float* __restrict__ B,
                                                   const float* __restrict__ bias,
                                                   void* __restrict__ Cv,
                                                   const float* __restrict__ atts,
                                                   const float* __restrict__ attd,
                                                   float* __restrict__ as_,
                                                   float* __restrict__ ad_,
                                                   int M, int Nn, int K) {
    __shared__ unsigned short AsU[64 * 128];
    __shared__ unsigned short BsU[64 * 128];
    char* AsB = (char*)AsU;
    char* BsB = (char*)BsU;
    const int tid = threadIdx.x;
    const int lane = tid & 63;
    const int wv = tid >> 6;
    const int row0 = blockIdx.y * 64, col0 = blockIdx.x * 64;
    const int r = lane & 15, q = lane >> 4;

    f32x4 acc[4];
#pragma unroll
    for (int i = 0; i < 4; i++) acc[i] = (f32x4){0.f, 0.f, 0.f, 0.f};

    for (int k0 = 0; k0 < K; k0 += 128) {
        __syncthreads();
        // stage A: rows row0..+63, k k0..+127 (fp32 -> bf16, swizzled)
#pragma unroll
        for (int it = 0; it < 8; it++) {
            int gq = tid + it * 256;       // 0..2047
            int row = gq >> 5;             // 0..63
            int k4 = (gq & 31) * 4;        // 0,4,..,124
            int gr = row0 + row;
            float4 v = make_float4(0.f, 0.f, 0.f, 0.f);
            if (gr < M) v = *(const float4*)(A + (size_t)gr * K + k0 + k4);
            ushort4 o;
            o.x = f2bf(v.x); o.y = f2bf(v.y); o.z = f2bf(v.z); o.w = f2bf(v.w);
            int byte = (row * 256 + k4 * 2) ^ ((row & 7) << 4);
            *(ushort4*)(AsB + byte) = o;
        }
        // stage B transposed: Bs[col][k]
#pragma unroll
        for (int it = 0; it < 8; it++) {
            int gq = tid + it * 256;       // 0..2047
            int kk = gq >> 4;              // 0..127
            int c4 = (gq & 15) * 4;        // 0,4,..,60
            float4 v = *(const float4*)(B + (size_t)(k0 + kk) * Nn + col0 + c4);
            float vv[4] = {v.x, v.y, v.z, v.w};
#pragma unroll
            for (int c = 0; c < 4; c++) {
                int col = c4 + c;
                int byte = (col * 256 + kk * 2) ^ ((col & 7) << 4);
                *(unsigned short*)(BsB + byte) = f2bf(vv[c]);
            }
        }
        __syncthreads();
#pragma unroll
        for (int ks = 0; ks < 4; ks++) {
            int kb = (ks * 32 + q * 8) * 2;
            int arow = wv * 16 + r;
            bf16x8 af = *(bf16x8*)(AsB + ((arow * 256 + kb) ^ ((arow & 7) << 4)));
#pragma unroll
            for (int nb = 0; nb < 4; nb++) {
                int col = nb * 16 + r;
                bf16x8 bfr = *(bf16x8*)(BsB + ((col * 256 + kb) ^ ((col & 7) << 4)));
                acc[nb] = __builtin_amdgcn_mfma_f32_16x16x32_bf16(af, bfr, acc[nb], 0, 0, 0);
            }
        }
    }
    // epilogue: D mapping col=lane&15, row=(lane>>4)*4+reg
#pragma unroll
    for (int nb = 0; nb < 4; nb++) {
        int col = col0 + nb * 16 + r;
#pragma unroll
        for (int j = 0; j < 4; j++) {
            int row = row0 + wv * 16 + q * 4 + j;
            if (row < M) {
                float v = acc[nb][j];
                if (ACT) { v += bias[col]; v = eluf(v); }
                if (OUTBF) ((unsigned short*)Cv)[(size_t)row * Nn + col] = f2bf(v);
                else       ((float*)Cv)[(size_t)row * Nn + col] = v;
            }
        }
    }
    if (ALPHA) {
        // this block's cols live in head hd, channels cb+nb*16+r
        int hd = col0 >> 7;
        int cb = col0 & 127;
        float ws[4], wd[4];
#pragma unroll
        for (int nb = 0; nb < 4; nb++) {
            ws[nb] = atts[hd * 128 + cb + nb * 16 + r];
            wd[nb] = attd[hd * 128 + cb + nb * 16 + r];
        }
#pragma unroll
        for (int j = 0; j < 4; j++) {
            float ps = 0.f, pd = 0.f;
#pragma unroll
            for (int nb = 0; nb < 4; nb++) {
                ps += acc[nb][j] * ws[nb];
                pd += acc[nb][j] * wd[nb];
            }
#pragma unroll
            for (int m = 1; m < 16; m <<= 1) {
                ps += __shfl_xor(ps, m);
                pd += __shfl_xor(pd, m);
            }
            if (r == 0) {
                int row = row0 + wv * 16 + q * 4 + j;
                if (row < M) {
                    atomicAdd(&as_[row * 8 + hd], ps);
                    atomicAdd(&ad_[row * 8 + hd], pd);
                }
            }
        }
    }
}

// ---------------------------------------------------------------------------
// Aggregation, 4-edge unrolled (8x 16B gathers in flight). One wave/node.
// Lane l: denom for head l&7; payload heads g,4+g (g=l>>4), channels
// 8*(l&15)..+7. No max-shift (|e| small; softmax ratio shift-invariant).
// ---------------------------------------------------------------------------
__global__ __launch_bounds__(256) void k_aggregate(const int* __restrict__ rowptr,
                                                   const int* __restrict__ csr,
                                                   const float* __restrict__ as_,
                                                   const float* __restrict__ ad_,
                                                   const ushort16* __restrict__ xl,
                                                   const float* __restrict__ hprev,
                                                   const float* __restrict__ bl,
                                                   const float* __restrict__ gam,
                                                   const float* __restrict__ bet,
                                                   float* __restrict__ hnext) {
    int lane = threadIdx.x & 63;
    int n = blockIdx.x * 4 + (threadIdx.x >> 6);
    if (n >= N_NODES) return;
    int h8 = lane & 7;
    int g = lane >> 4;
    float adh = ad_[n * 8 + h8];
    int start = rowptr[n], end = rowptr[n + 1];

    float acc0[8] = {}, acc1[8] = {};
    float denom = 0.f;
    int e = start;
    for (; e + 3 < end; e += 4) {
        int s0 = csr[e], s1 = csr[e + 1], s2 = csr[e + 2], s3 = csr[e + 3];
        float a0 = as_[s0 * 8 + h8], a1 = as_[s1 * 8 + h8];
        float a2 = as_[s2 * 8 + h8], a3 = as_[s3 * 8 + h8];
        const uint4* xp0 = (const uint4*)(xl + (size_t)s0 * 1024);
        const uint4* xp1 = (const uint4*)(xl + (size_t)s1 * 1024);
        const uint4* xp2 = (const uint4*)(xl + (size_t)s2 * 1024);
        const uint4* xp3 = (const uint4*)(xl + (size_t)s3 * 1024);
        uint4 u0a = xp0[lane], u1a = xp0[64 + lane];
        uint4 u0b = xp1[lane], u1b = xp1[64 + lane];
        uint4 u0c = xp2[lane], u1c = xp2[64 + lane];
        uint4 u0d = xp3[lane], u1d = xp3[64 + lane];
        float ee0 = __expf(lrelu(a0 + adh));
        float ee1 = __expf(lrelu(a1 + adh));
        float ee2 = __expf(lrelu(a2 + adh));
        float ee3 = __expf(lrelu(a3 + adh));
        denom += (ee0 + ee1) + (ee2 + ee3);
        float e0a = __shfl(ee0, g), e1a = __shfl(ee0, 4 + g);
        float e0b = __shfl(ee1, g), e1b = __shfl(ee1, 4 + g);
        float e0c = __shfl(ee2, g), e1c = __shfl(ee2, 4 + g);
        float e0d = __shfl(ee3, g), e1d = __shfl(ee3, 4 + g);
        acc0[0] += e0a * blo(u0a.x) + e0b * blo(u0b.x) + e0c * blo(u0c.x) + e0d * blo(u0d.x);
        acc0[1] += e0a * bhi(u0a.x) + e0b * bhi(u0b.x) + e0c * bhi(u0c.x) + e0d * bhi(u0d.x);
        acc0[2] += e0a * blo(u0a.y) + e0b * blo(u0b.y) + e0c * blo(u0c.y) + e0d * blo(u0d.y);
        acc0[3] += e0a * bhi(u0a.y) + e0b * bhi(u0b.y) + e0c * bhi(u0c.y) + e0d * bhi(u0d.y);
        acc0[4] += e0a * blo(u0a.z) + e0b * blo(u0b.z) + e0c * blo(u0c.z) + e0d * blo(u0d.z);
        acc0[5] += e0a * bhi(u0a.z) + e0b * bhi(u0b.z) + e0c * bhi(u0c.z) + e0d * bhi(u0d.z);
        acc0[6] += e0a * blo(u0a.w) + e0b * blo(u0b.w) + e0c * blo(u0c.w) + e0d * blo(u0d.w);
        acc0[7] += e0a * bhi(u0a.w) + e0b * bhi(u0b.w) + e0c * bhi(u0c.w) + e0d * bhi(u0d.w);
        acc1[0] += e1a * blo(u1a.x) + e1b * blo(u1b.x) + e1c * blo(u1c.x) + e1d * blo(u1d.x);
        acc1[1] += e1a * bhi(u1a.x) + e1b * bhi(u1b.x) + e1c * bhi(u1c.x) + e1d * bhi(u1d.x);
        acc1[2] += e1a * blo(u1a.y) + e1b * blo(u1b.y) + e1c * blo(u1c.y) + e1d * blo(u1d.y);
        acc1[3] += e1a * bhi(u1a.y) + e1b * bhi(u1b.y) + e1c * bhi(u1c.y) + e1d * bhi(u1d.y);
        acc1[4] += e1a * blo(u1a.z) + e1b * blo(u1b.z) + e1c * blo(u1c.z) + e1d * blo(u1d.z);
        acc1[5] += e1a * bhi(u1a.z) + e1b * bhi(u1b.z) + e1c * bhi(u1c.z) + e1d * bhi(u1d.z);
        acc1[6] += e1a * blo(u1a.w) + e1b * blo(u1b.w) + e1c * blo(u1c.w) + e1d * blo(u1d.w);
        acc1[7] += e1a * bhi(u1a.w) + e1b * bhi(u1b.w) + e1c * bhi(u1c.w) + e1d * bhi(u1d.w);
    }
    for (; e < end; ++e) {  // tail (0..3 edges)
        int s0 = csr[e];
        float a0 = as_[s0 * 8 + h8];
        const uint4* xp0 = (const uint4*)(xl + (size_t)s0 * 1024);
        uint4 u0a = xp0[lane], u1a = xp0[64 + lane];
        float ee0 = __expf(lrelu(a0 + adh));
        denom += ee0;
        float e0a = __shfl(ee0, g), e1a = __shfl(ee0, 4 + g);
        acc0[0] += e0a * blo(u0a.x); acc0[1] += e0a * bhi(u0a.x);
        acc0[2] += e0a * blo(u0a.y); acc0[3] += e0a * bhi(u0a.y);
        acc0[4] += e0a * blo(u0a.z); acc0[5] += e0a * bhi(u0a.z);
        acc0[6] += e0a * blo(u0a.w); acc0[7] += e0a * bhi(u0a.w);
        acc1[0] += e1a * blo(u1a.x); acc1[1] += e1a * bhi(u1a.x);
        acc1[2] += e1a * blo(u1a.y); acc1[3] += e1a * bhi(u1a.y);
        acc1[4] += e1a * blo(u1a.z); acc1[5] += e1a * bhi(u1a.z);
        acc1[6] += e1a * blo(u1a.w); acc1[7] += e1a * bhi(u1a.w);
    }

    float d0 = __shfl(denom, g);
    float d1 = __shfl(denom, 4 + g);
    float r0 = 1.f / (d0 + 1e-16f);
    float r1 = 1.f / (d1 + 1e-16f);
    float sum[8];
#pragma unroll
    for (int i = 0; i < 8; i++) sum[i] = acc0[i] * r0 + acc1[i] * r1;
#pragma unroll
    for (int i = 0; i < 8; i++) {
        sum[i] += __shfl_xor(sum[i], 16);
        sum[i] += __shfl_xor(sum[i], 32);
    }

    if (lane < 16) {
        int c = 8 * lane;
        float o[8];
#pragma unroll
        for (int t = 0; t < 8; t++) {
            float m = sum[t] * 0.125f + bl[c + t];              // mean heads + bias
            float gg = gam[c + t] * (m * BN_INV) + bet[c + t];  // BN eval
            float z = 0.9f * gg + 0.1f * hprev[(size_t)n * 128 + c + t];
            o[t] = eluf(z);
        }
        *(float4*)(hnext + (size_t)n * 128 + c)     = make_float4(o[0], o[1], o[2], o[3]);
        *(float4*)(hnext + (size_t)n * 128 + c + 4) = make_float4(o[4], o[5], o[6], o[7]);
    }
}

// ---------------------------------------------------------------------------
// Classifier head: out = elu(h@W1+b1) @ W2 + b2, one wave per node.
// ---------------------------------------------------------------------------
__global__ __launch_bounds__(256) void k_classifier(const float* __restrict__ h,
                                                    const float* __restrict__ W1,
                                                    const float* __restrict__ b1,
                                                    const float* __restrict__ W2,
                                                    const float* __restrict__ b2,
                                                    float* __restrict__ out) {
    __shared__ float sW1[128 * 64];
    __shared__ float sW2[128];
    __shared__ float sb1[64];
    __shared__ float sb2[2];
    for (int i = threadIdx.x; i < 2048; i += 256)
        *(float4*)&sW1[i * 4] = *(const float4*)(W1 + i * 4);
    if (threadIdx.x < 64) sb1[threadIdx.x] = b1[threadIdx.x];
    if (threadIdx.x < 128) sW2[threadIdx.x] = W2[threadIdx.x];
    if (threadIdx.x < 2) sb2[threadIdx.x] = b2[threadIdx.x];
    __syncthreads();
    int lane = threadIdx.x & 63;
    int n = blockIdx.x * 4 + (threadIdx.x >> 6);
    if (n >= N_NODES) return;
    float h0 = h[(size_t)n * 128 + lane];
    float h1 = h[(size_t)n * 128 + 64 + lane];
    float acc = sb1[lane];
#pragma unroll
    for (int c = 0; c < 64; c++) acc += __shfl(h0, c) * sW1[c * 64 + lane];
#pragma unroll
    for (int c = 0; c < 64; c++) acc += __shfl(h1, c) * sW1[(64 + c) * 64 + lane];
    acc = eluf(acc);
    float p0 = acc * sW2[lane * 2 + 0];
    float p1 = acc * sW2[lane * 2 + 1];
#pragma unroll
    for (int m = 1; m < 64; m <<= 1) {
        p0 += __shfl_xor(p0, m);
        p1 += __shfl_xor(p1, m);
    }
    if (lane == 0) {
        out[(size_t)n * 2 + 0] = p0 + sb2[0];
        out[(size_t)n * 2 + 1] = p1 + sb2[1];
    }
}

// ---------------------------------------------------------------------------
extern "C" void kernel_launch(void* const* d_in, const int* in_sizes, int n_in,
                              void* d_out, int out_size, void* d_ws, size_t ws_size,
                              hipStream_t stream) {
    const float* x       = (const float*)d_in[0];
    const int* ei        = (const int*)d_in[1];   // int32 per harness convention
    const float* Wp      = (const float*)d_in[2];
    const float* bp      = (const float*)d_in[3];
    const float* Wl      = (const float*)d_in[4];
    const float* atts    = (const float*)d_in[5];
    const float* attd    = (const float*)d_in[6];
    const float* bl      = (const float*)d_in[7];
    const float* gam     = (const float*)d_in[8];
    const float* bet     = (const float*)d_in[9];
    const float* W1      = (const float*)d_in[10];
    const float* b1      = (const float*)d_in[11];
    const float* W2      = (const float*)d_in[12];
    const float* b2      = (const float*)d_in[13];
    float* out = (float*)d_out;

    char* w = (char*)d_ws;
    auto carve = [&](size_t bytes) -> void* {
        void* p = (void*)w;
        w += (bytes + 255) & ~(size_t)255;
        return p;
    };
    int* deg        = (int*)carve((size_t)N_NODES * 4);
    int* rowptr     = (int*)carve((size_t)(N_NODES + 1) * 4);
    int* cursor     = (int*)carve((size_t)N_NODES * 4);
    int* csr        = (int*)carve((size_t)(N_EDGES + N_NODES) * 4);
    float* as_      = (float*)carve((size_t)N_NODES * 8 * 4);   // contiguous with ad_
    float* ad_      = (float*)carve((size_t)N_NODES * 8 * 4);
    ushort16* xl    = (ushort16*)carve((size_t)N_NODES * 1024 * 2);  // bf16
    float* hA       = (float*)carve((size_t)N_NODES * 128 * 4);
    float* hB       = (float*)carve((size_t)N_NODES * 128 * 4);

    hipMemsetAsync(deg, 0, (size_t)N_NODES * 4, stream);
    k_deg<<<(N_EDGES + 255) / 256, 256, 0, stream>>>(ei, deg);
    k_scan<<<1, 1024, 0, stream>>>(deg, rowptr, cursor);
    k_scatter<<<(N_EDGES + N_NODES + 255) / 256, 256, 0, stream>>>(ei, cursor, csr);

    // h = elu(x @ Wp + bp)  (bf16-MFMA, fp32 out)
    k_gemm_mfma<1, 0, 0><<<dim3(2, 157), 256, 0, stream>>>(
        x, Wp, bp, hA, nullptr, nullptr, nullptr, nullptr, N_NODES, 128, 512);

    float* hc = hA;
    float* hn = hB;
    for (int l = 0; l < NLAYER; l++) {
        // zero alpha accumulators (as_ and ad_ are contiguous: one memset)
        hipMemsetAsync(as_, 0, (size_t)N_NODES * 8 * 4 * 2, stream);
        // xl = hc @ Wl[l]  (bf16 out) + fused alpha partials
        k_gemm_mfma<0, 1, 1><<<dim3(16, 157), 256, 0, stream>>>(
            hc, Wl + (size_t)l * 128 * 1024, nullptr, xl,
            atts + l * 1024, attd + l * 1024, as_, ad_, N_NODES, 1024, 128);
        k_aggregate<<<2500, 256, 0, stream>>>(rowptr, csr, as_, ad_, xl, hc, bl + l * 128,
                                              gam + l * 128, bet + l * 128, hn);
        float* tmp = hc; hc = hn; hn = tmp;
    }
    k_classifier<<<2500, 256, 0, stream>>>(hc, W1, b1, W2, b2, out);
}

// Round 11
// 501.938 us; speedup vs baseline: 1.0839x; 1.0839x over previous
//
#include <hip/hip_runtime.h>
#include <cstdint>
#include <cstddef>

#define N_NODES 10000
#define N_EDGES 160000
#define DIM_IN  512
#define HIDDIM  128
#define NHEAD   8
#define NLAYER  4

typedef unsigned int   uint32;
typedef unsigned short ushort16;
typedef __attribute__((ext_vector_type(8))) short bf16x8;
typedef __attribute__((ext_vector_type(4))) float f32x4;

static __device__ __forceinline__ float eluf(float v)  { return v > 0.f ? v : expm1f(v); }
static __device__ __forceinline__ float lrelu(float v) { return v >= 0.f ? v : 0.2f * v; }
static __device__ __forceinline__ ushort16 f2bf(float f) {  // RNE fp32->bf16
    uint32 u = __float_as_uint(f);
    u += 0x7fffu + ((u >> 16) & 1u);
    return (ushort16)(u >> 16);
}
static __device__ __forceinline__ float blo(uint32 u) { return __uint_as_float(u << 16); }
static __device__ __forceinline__ float bhi(uint32 u) { return __uint_as_float(u & 0xffff0000u); }

#define BN_INV 0.9999950000374997f  /* 1/sqrt(1+1e-5) */

// ---------------------------------------------------------------------------
// CSR build
// ---------------------------------------------------------------------------
__global__ void k_deg(const int* __restrict__ ei, int* __restrict__ deg) {
    int t = blockIdx.x * 256 + threadIdx.x;
    if (t < N_EDGES) atomicAdd(&deg[ei[N_EDGES + t]], 1);
}

__global__ __launch_bounds__(1024) void k_scan(const int* __restrict__ deg,
                                               int* __restrict__ rowptr,
                                               int* __restrict__ cursor) {
    __shared__ int sd[1024];
    __shared__ int carry;
    int tid = threadIdx.x;
    if (tid == 0) { carry = 0; rowptr[0] = 0; }
    __syncthreads();
    for (int base = 0; base < N_NODES; base += 1024) {
        int i = base + tid;
        int v = (i < N_NODES) ? (deg[i] + 1) : 0;  // +1 = self loop
        sd[tid] = v;
        __syncthreads();
        for (int ofs = 1; ofs < 1024; ofs <<= 1) {
            int t = (tid >= ofs) ? sd[tid - ofs] : 0;
            __syncthreads();
            sd[tid] += t;
            __syncthreads();
        }
        int inc = sd[tid] + carry;
        if (i < N_NODES) { rowptr[i + 1] = inc; cursor[i] = inc - v; }
        __syncthreads();
        if (tid == 1023) carry = inc;
        __syncthreads();
    }
}

__global__ void k_scatter(const int* __restrict__ ei, int* __restrict__ cursor,
                          int* __restrict__ csr) {
    int t = blockIdx.x * 256 + threadIdx.x;
    if (t < N_EDGES) {
        int s = ei[t];
        int d = ei[N_EDGES + t];
        int p = atomicAdd(&cursor[d], 1);
        csr[p] = s;
    } else if (t < N_EDGES + N_NODES) {
        int n = t - N_EDGES;
        int p = atomicAdd(&cursor[n], 1);
        csr[p] = n;  // self loop
    }
}

// ---------------------------------------------------------------------------
// bf16-MFMA GEMM (round-8 proven version). BM=BN=64, 4 waves.
// XOR swizzle byte^=(row&7)<<4 -> conflict-free stride-256B fragment reads.
// ---------------------------------------------------------------------------
template <int ACT, int OUTBF>
__global__ __launch_bounds__(256) void k_gemm_mfma(const float* __restrict__ A,
                                                   const float* __restrict__ B,
                                                   const float* __restrict__ bias,
                                                   void* __restrict__ Cv,
                                                   int M, int Nn, int K) {
    __shared__ unsigned short AsU[64 * 128];
    __shared__ unsigned short BsU[64 * 128];
    char* AsB = (char*)AsU;
    char* BsB = (char*)BsU;
    const int tid = threadIdx.x;
    const int lane = tid & 63;
    const int wv = tid >> 6;
    const int row0 = blockIdx.y * 64, col0 = blockIdx.x * 64;
    const int r = lane & 15, q = lane >> 4;

    f32x4 acc[4];
#pragma unroll
    for (int i = 0; i < 4; i++) acc[i] = (f32x4){0.f, 0.f, 0.f, 0.f};

    for (int k0 = 0; k0 < K; k0 += 128) {
        __syncthreads();
        // stage A: rows row0..+63, k k0..+127 (fp32 -> bf16, swizzled)
#pragma unroll
        for (int it = 0; it < 8; it++) {
            int gq = tid + it * 256;       // 0..2047
            int row = gq >> 5;             // 0..63
            int k4 = (gq & 31) * 4;        // 0,4,..,124
            int gr = row0 + row;
            float4 v = make_float4(0.f, 0.f, 0.f, 0.f);
            if (gr < M) v = *(const float4*)(A + (size_t)gr * K + k0 + k4);
            ushort4 o;
            o.x = f2bf(v.x); o.y = f2bf(v.y); o.z = f2bf(v.z); o.w = f2bf(v.w);
            int byte = (row * 256 + k4 * 2) ^ ((row & 7) << 4);
            *(ushort4*)(AsB + byte) = o;
        }
        // stage B transposed: Bs[col][k]
#pragma unroll
        for (int it = 0; it < 8; it++) {
            int gq = tid + it * 256;       // 0..2047
            int kk = gq >> 4;              // 0..127
            int c4 = (gq & 15) * 4;        // 0,4,..,60
            float4 v = *(const float4*)(B + (size_t)(k0 + kk) * Nn + col0 + c4);
            float vv[4] = {v.x, v.y, v.z, v.w};
#pragma unroll
            for (int c = 0; c < 4; c++) {
                int col = c4 + c;
                int byte = (col * 256 + kk * 2) ^ ((col & 7) << 4);
                *(unsigned short*)(BsB + byte) = f2bf(vv[c]);
            }
        }
        __syncthreads();
#pragma unroll
        for (int ks = 0; ks < 4; ks++) {
            int kb = (ks * 32 + q * 8) * 2;
            int arow = wv * 16 + r;
            bf16x8 af = *(bf16x8*)(AsB + ((arow * 256 + kb) ^ ((arow & 7) << 4)));
#pragma unroll
            for (int nb = 0; nb < 4; nb++) {
                int col = nb * 16 + r;
                bf16x8 bfr = *(bf16x8*)(BsB + ((col * 256 + kb) ^ ((col & 7) << 4)));
                acc[nb] = __builtin_amdgcn_mfma_f32_16x16x32_bf16(af, bfr, acc[nb], 0, 0, 0);
            }
        }
    }
    // epilogue: D mapping col=lane&15, row=(lane>>4)*4+reg
#pragma unroll
    for (int nb = 0; nb < 4; nb++) {
        int col = col0 + nb * 16 + r;
#pragma unroll
        for (int j = 0; j < 4; j++) {
            int row = row0 + wv * 16 + q * 4 + j;
            if (row < M) {
                float v = acc[nb][j];
                if (ACT) { v += bias[col]; v = eluf(v); }
                if (OUTBF) ((unsigned short*)Cv)[(size_t)row * Nn + col] = f2bf(v);
                else       ((float*)Cv)[(size_t)row * Nn + col] = v;
            }
        }
    }
}

// ---------------------------------------------------------------------------
// alpha_s[n,h] = sum_c xl[n,h,c]*att_src[h,c] (xl bf16). One wave/node.
// ---------------------------------------------------------------------------
__global__ __launch_bounds__(256) void k_alphas(const ushort16* __restrict__ xl,
                                                const float* __restrict__ atts,
                                                const float* __restrict__ attd,
                                                float* __restrict__ as_,
                                                float* __restrict__ ad_) {
    int lane = threadIdx.x & 63;
    int n = blockIdx.x * 4 + (threadIdx.x >> 6);
    if (n >= N_NODES) return;
    int g = lane >> 4;          // 0..3
    int c8 = 8 * (lane & 15);   // channel base
    const uint4* xp = (const uint4*)(xl + (size_t)n * 1024);
    float ss[2], sd[2];
#pragma unroll
    for (int j = 0; j < 2; j++) {
        int head = 4 * j + g;
        uint4 u = xp[j * 64 + lane];
        const float4* ap = (const float4*)(atts + head * 128 + c8);
        const float4* bp = (const float4*)(attd + head * 128 + c8);
        float4 a0 = ap[0], a1 = ap[1];
        float4 b0 = bp[0], b1 = bp[1];
        float x0 = blo(u.x), x1 = bhi(u.x), x2 = blo(u.y), x3 = bhi(u.y);
        float x4 = blo(u.z), x5 = bhi(u.z), x6 = blo(u.w), x7 = bhi(u.w);
        ss[j] = x0 * a0.x + x1 * a0.y + x2 * a0.z + x3 * a0.w +
                x4 * a1.x + x5 * a1.y + x6 * a1.z + x7 * a1.w;
        sd[j] = x0 * b0.x + x1 * b0.y + x2 * b0.z + x3 * b0.w +
                x4 * b1.x + x5 * b1.y + x6 * b1.z + x7 * b1.w;
    }
#pragma unroll
    for (int m = 1; m < 16; m <<= 1) {
#pragma unroll
        for (int j = 0; j < 2; j++) {
            ss[j] += __shfl_xor(ss[j], m);
            sd[j] += __shfl_xor(sd[j], m);
        }
    }
    if ((lane & 15) == 0) {
        as_[n * 8 + g]     = ss[0];
        as_[n * 8 + 4 + g] = ss[1];
        ad_[n * 8 + g]     = sd[0];
        ad_[n * 8 + 4 + g] = sd[1];
    }
}

// ---------------------------------------------------------------------------
// Aggregation, wave-split: block = 256 thr = 4 waves = 2 nodes x 2 waves.
// Wave (par=0/1) of node slot handles edges start+par, start+par+2, ... —
// halves the serial dependent-gather chain per wave and doubles wave count.
// Partials (acc0[8], acc1[8], denom) combined via LDS + one uniform barrier.
// Per-wave body: 2-edge unroll (4 gathers in flight), bf16 payload.
// ---------------------------------------------------------------------------
__global__ __launch_bounds__(256) void k_aggregate(const int* __restrict__ rowptr,
                                                   const int* __restrict__ csr,
                                                   const float* __restrict__ as_,
                                                   const float* __restrict__ ad_,
                                                   const ushort16* __restrict__ xl,
                                                   const float* __restrict__ hprev,
                                                   const float* __restrict__ bl,
                                                   const float* __restrict__ gam,
                                                   const float* __restrict__ bet,
                                                   float* __restrict__ hnext) {
    __shared__ float cmb[2][64][17];   // [node slot][lane][acc0 x8, acc1 x8, denom]
    int tid = threadIdx.x;
    int lane = tid & 63;
    int wv = tid >> 6;
    int which = wv >> 1;               // node slot in block
    int par = wv & 1;                  // edge parity handled by this wave
    int n = blockIdx.x * 2 + which;    // grid = N/2 exactly; n < N always
    int h8 = lane & 7;
    int g = lane >> 4;
    float adh = ad_[n * 8 + h8];
    int start = rowptr[n], end = rowptr[n + 1];

    float acc0[8] = {}, acc1[8] = {};
    float denom = 0.f;
    int e = start + par;
    for (; e + 2 < end; e += 4) {      // edges e and e+2 (same parity class)
        int s0 = csr[e], s1 = csr[e + 2];
        float a0 = as_[s0 * 8 + h8];
        float a1 = as_[s1 * 8 + h8];
        const uint4* xp0 = (const uint4*)(xl + (size_t)s0 * 1024);
        const uint4* xp1 = (const uint4*)(xl + (size_t)s1 * 1024);
        uint4 u0a = xp0[lane], u1a = xp0[64 + lane];
        uint4 u0b = xp1[lane], u1b = xp1[64 + lane];
        float ee0 = __expf(lrelu(a0 + adh));
        float ee1 = __expf(lrelu(a1 + adh));
        denom += ee0 + ee1;
        float e0a = __shfl(ee0, g), e1a = __shfl(ee0, 4 + g);
        float e0b = __shfl(ee1, g), e1b = __shfl(ee1, 4 + g);
        acc0[0] += e0a * blo(u0a.x) + e0b * blo(u0b.x);
        acc0[1] += e0a * bhi(u0a.x) + e0b * bhi(u0b.x);
        acc0[2] += e0a * blo(u0a.y) + e0b * blo(u0b.y);
        acc0[3] += e0a * bhi(u0a.y) + e0b * bhi(u0b.y);
        acc0[4] += e0a * blo(u0a.z) + e0b * blo(u0b.z);
        acc0[5] += e0a * bhi(u0a.z) + e0b * bhi(u0b.z);
        acc0[6] += e0a * blo(u0a.w) + e0b * blo(u0b.w);
        acc0[7] += e0a * bhi(u0a.w) + e0b * bhi(u0b.w);
        acc1[0] += e1a * blo(u1a.x) + e1b * blo(u1b.x);
        acc1[1] += e1a * bhi(u1a.x) + e1b * bhi(u1b.x);
        acc1[2] += e1a * blo(u1a.y) + e1b * blo(u1b.y);
        acc1[3] += e1a * bhi(u1a.y) + e1b * bhi(u1b.y);
        acc1[4] += e1a * blo(u1a.z) + e1b * blo(u1b.z);
        acc1[5] += e1a * bhi(u1a.z) + e1b * bhi(u1b.z);
        acc1[6] += e1a * blo(u1a.w) + e1b * blo(u1b.w);
        acc1[7] += e1a * bhi(u1a.w) + e1b * bhi(u1b.w);
    }
    for (; e < end; e += 2) {          // parity-class tail (<=2 single edges)
        int s0 = csr[e];
        float a0 = as_[s0 * 8 + h8];
        const uint4* xp0 = (const uint4*)(xl + (size_t)s0 * 1024);
        uint4 u0a = xp0[lane], u1a = xp0[64 + lane];
        float ee0 = __expf(lrelu(a0 + adh));
        denom += ee0;
        float e0a = __shfl(ee0, g), e1a = __shfl(ee0, 4 + g);
        acc0[0] += e0a * blo(u0a.x); acc0[1] += e0a * bhi(u0a.x);
        acc0[2] += e0a * blo(u0a.y); acc0[3] += e0a * bhi(u0a.y);
        acc0[4] += e0a * blo(u0a.z); acc0[5] += e0a * bhi(u0a.z);
        acc0[6] += e0a * blo(u0a.w); acc0[7] += e0a * bhi(u0a.w);
        acc1[0] += e1a * blo(u1a.x); acc1[1] += e1a * bhi(u1a.x);
        acc1[2] += e1a * blo(u1a.y); acc1[3] += e1a * bhi(u1a.y);
        acc1[4] += e1a * blo(u1a.z); acc1[5] += e1a * bhi(u1a.z);
        acc1[6] += e1a * blo(u1a.w); acc1[7] += e1a * bhi(u1a.w);
    }

    if (par == 1) {                    // secondary wave publishes partials
#pragma unroll
        for (int i = 0; i < 8; i++) {
            cmb[which][lane][i]     = acc0[i];
            cmb[which][lane][8 + i] = acc1[i];
        }
        cmb[which][lane][16] = denom;
    }
    __syncthreads();                   // uniform: every wave passes exactly once
    if (par == 1) return;
#pragma unroll
    for (int i = 0; i < 8; i++) {
        acc0[i] += cmb[which][lane][i];
        acc1[i] += cmb[which][lane][8 + i];
    }
    denom += cmb[which][lane][16];

    float d0 = __shfl(denom, g);
    float d1 = __shfl(denom, 4 + g);
    float r0 = 1.f / (d0 + 1e-16f);
    float r1 = 1.f / (d1 + 1e-16f);
    float sum[8];
#pragma unroll
    for (int i = 0; i < 8; i++) sum[i] = acc0[i] * r0 + acc1[i] * r1;
#pragma unroll
    for (int i = 0; i < 8; i++) {
        sum[i] += __shfl_xor(sum[i], 16);
        sum[i] += __shfl_xor(sum[i], 32);
    }

    if (lane < 16) {
        int c = 8 * lane;
        float o[8];
#pragma unroll
        for (int t = 0; t < 8; t++) {
            float m = sum[t] * 0.125f + bl[c + t];              // mean heads + bias
            float gg = gam[c + t] * (m * BN_INV) + bet[c + t];  // BN eval
            float z = 0.9f * gg + 0.1f * hprev[(size_t)n * 128 + c + t];
            o[t] = eluf(z);
        }
        *(float4*)(hnext + (size_t)n * 128 + c)     = make_float4(o[0], o[1], o[2], o[3]);
        *(float4*)(hnext + (size_t)n * 128 + c + 4) = make_float4(o[4], o[5], o[6], o[7]);
    }
}

// ---------------------------------------------------------------------------
// Classifier head: out = elu(h@W1+b1) @ W2 + b2, one wave per node.
// ---------------------------------------------------------------------------
__global__ __launch_bounds__(256) void k_classifier(const float* __restrict__ h,
                                                    const float* __restrict__ W1,
                                                    const float* __restrict__ b1,
                                                    const float* __restrict__ W2,
                                                    const float* __restrict__ b2,
                                                    float* __restrict__ out) {
    __shared__ float sW1[128 * 64];
    __shared__ float sW2[128];
    __shared__ float sb1[64];
    __shared__ float sb2[2];
    for (int i = threadIdx.x; i < 2048; i += 256)
        *(float4*)&sW1[i * 4] = *(const float4*)(W1 + i * 4);
    if (threadIdx.x < 64) sb1[threadIdx.x] = b1[threadIdx.x];
    if (threadIdx.x < 128) sW2[threadIdx.x] = W2[threadIdx.x];
    if (threadIdx.x < 2) sb2[threadIdx.x] = b2[threadIdx.x];
    __syncthreads();
    int lane = threadIdx.x & 63;
    int n = blockIdx.x * 4 + (threadIdx.x >> 6);
    if (n >= N_NODES) return;
    float h0 = h[(size_t)n * 128 + lane];
    float h1 = h[(size_t)n * 128 + 64 + lane];
    float acc = sb1[lane];
#pragma unroll
    for (int c = 0; c < 64; c++) acc += __shfl(h0, c) * sW1[c * 64 + lane];
#pragma unroll
    for (int c = 0; c < 64; c++) acc += __shfl(h1, c) * sW1[(64 + c) * 64 + lane];
    acc = eluf(acc);
    float p0 = acc * sW2[lane * 2 + 0];
    float p1 = acc * sW2[lane * 2 + 1];
#pragma unroll
    for (int m = 1; m < 64; m <<= 1) {
        p0 += __shfl_xor(p0, m);
        p1 += __shfl_xor(p1, m);
    }
    if (lane == 0) {
        out[(size_t)n * 2 + 0] = p0 + sb2[0];
        out[(size_t)n * 2 + 1] = p1 + sb2[1];
    }
}

// ---------------------------------------------------------------------------
extern "C" void kernel_launch(void* const* d_in, const int* in_sizes, int n_in,
                              void* d_out, int out_size, void* d_ws, size_t ws_size,
                              hipStream_t stream) {
    const float* x       = (const float*)d_in[0];
    const int* ei        = (const int*)d_in[1];   // int32 per harness convention
    const float* Wp      = (const float*)d_in[2];
    const float* bp      = (const float*)d_in[3];
    const float* Wl      = (const float*)d_in[4];
    const float* atts    = (const float*)d_in[5];
    const float* attd    = (const float*)d_in[6];
    const float* bl      = (const float*)d_in[7];
    const float* gam     = (const float*)d_in[8];
    const float* bet     = (const float*)d_in[9];
    const float* W1      = (const float*)d_in[10];
    const float* b1      = (const float*)d_in[11];
    const float* W2      = (const float*)d_in[12];
    const float* b2      = (const float*)d_in[13];
    float* out = (float*)d_out;

    char* w = (char*)d_ws;
    auto carve = [&](size_t bytes) -> void* {
        void* p = (void*)w;
        w += (bytes + 255) & ~(size_t)255;
        return p;
    };
    int* deg        = (int*)carve((size_t)N_NODES * 4);
    int* rowptr     = (int*)carve((size_t)(N_NODES + 1) * 4);
    int* cursor     = (int*)carve((size_t)N_NODES * 4);
    int* csr        = (int*)carve((size_t)(N_EDGES + N_NODES) * 4);
    float* as_      = (float*)carve((size_t)N_NODES * 8 * 4);
    float* ad_      = (float*)carve((size_t)N_NODES * 8 * 4);
    ushort16* xl    = (ushort16*)carve((size_t)N_NODES * 1024 * 2);  // bf16
    float* hA       = (float*)carve((size_t)N_NODES * 128 * 4);
    float* hB       = (float*)carve((size_t)N_NODES * 128 * 4);

    hipMemsetAsync(deg, 0, (size_t)N_NODES * 4, stream);
    k_deg<<<(N_EDGES + 255) / 256, 256, 0, stream>>>(ei, deg);
    k_scan<<<1, 1024, 0, stream>>>(deg, rowptr, cursor);
    k_scatter<<<(N_EDGES + N_NODES + 255) / 256, 256, 0, stream>>>(ei, cursor, csr);

    // h = elu(x @ Wp + bp)  (bf16-MFMA, fp32 out)
    k_gemm_mfma<1, 0><<<dim3(2, 157), 256, 0, stream>>>(x, Wp, bp, hA, N_NODES, 128, 512);

    float* hc = hA;
    float* hn = hB;
    for (int l = 0; l < NLAYER; l++) {
        // xl = hc @ Wl[l]  (bf16-MFMA, bf16 out)
        k_gemm_mfma<0, 1><<<dim3(16, 157), 256, 0, stream>>>(hc, Wl + (size_t)l * 128 * 1024,
                                                             nullptr, xl, N_NODES, 1024, 128);
        k_alphas<<<2500, 256, 0, stream>>>(xl, atts + l * 1024, attd + l * 1024, as_, ad_);
        k_aggregate<<<5000, 256, 0, stream>>>(rowptr, csr, as_, ad_, xl, hc, bl + l * 128,
                                              gam + l * 128, bet + l * 128, hn);
        float* tmp = hc; hc = hn; hn = tmp;
    }
    k_classifier<<<2500, 256, 0, stream>>>(hc, W1, b1, W2, b2, out);
}

// Round 13
// 483.522 us; speedup vs baseline: 1.1252x; 1.0381x over previous
//
#include <hip/hip_runtime.h>
#include <cstdint>
#include <cstddef>

#define N_NODES 10000
#define N_EDGES 160000
#define DIM_IN  512
#define HIDDIM  128
#define NHEAD   8
#define NLAYER  4

typedef unsigned int   uint32;
typedef unsigned short ushort16;
typedef __attribute__((ext_vector_type(8))) short bf16x8;
typedef __attribute__((ext_vector_type(4))) float f32x4;

static __device__ __forceinline__ float eluf(float v)  { return v > 0.f ? v : expm1f(v); }
static __device__ __forceinline__ float lrelu(float v) { return v >= 0.f ? v : 0.2f * v; }
static __device__ __forceinline__ ushort16 f2bf(float f) {  // RNE fp32->bf16
    uint32 u = __float_as_uint(f);
    u += 0x7fffu + ((u >> 16) & 1u);
    return (ushort16)(u >> 16);
}
static __device__ __forceinline__ float blo(uint32 u) { return __uint_as_float(u << 16); }
static __device__ __forceinline__ float bhi(uint32 u) { return __uint_as_float(u & 0xffff0000u); }

#define BN_INV 0.9999950000374997f  /* 1/sqrt(1+1e-5) */

// ---------------------------------------------------------------------------
// CSR build
// ---------------------------------------------------------------------------
__global__ void k_deg(const int* __restrict__ ei, int* __restrict__ deg) {
    int t = blockIdx.x * 256 + threadIdx.x;
    if (t < N_EDGES) atomicAdd(&deg[ei[N_EDGES + t]], 1);
}

__global__ __launch_bounds__(1024) void k_scan(const int* __restrict__ deg,
                                               int* __restrict__ rowptr,
                                               int* __restrict__ cursor) {
    __shared__ int sd[1024];
    __shared__ int carry;
    int tid = threadIdx.x;
    if (tid == 0) { carry = 0; rowptr[0] = 0; }
    __syncthreads();
    for (int base = 0; base < N_NODES; base += 1024) {
        int i = base + tid;
        int v = (i < N_NODES) ? (deg[i] + 1) : 0;  // +1 = self loop
        sd[tid] = v;
        __syncthreads();
        for (int ofs = 1; ofs < 1024; ofs <<= 1) {
            int t = (tid >= ofs) ? sd[tid - ofs] : 0;
            __syncthreads();
            sd[tid] += t;
            __syncthreads();
        }
        int inc = sd[tid] + carry;
        if (i < N_NODES) { rowptr[i + 1] = inc; cursor[i] = inc - v; }
        __syncthreads();
        if (tid == 1023) carry = inc;
        __syncthreads();
    }
}

__global__ void k_scatter(const int* __restrict__ ei, int* __restrict__ cursor,
                          int* __restrict__ csr) {
    int t = blockIdx.x * 256 + threadIdx.x;
    if (t < N_EDGES) {
        int s = ei[t];
        int d = ei[N_EDGES + t];
        int p = atomicAdd(&cursor[d], 1);
        csr[p] = s;
    } else if (t < N_EDGES + N_NODES) {
        int n = t - N_EDGES;
        int p = atomicAdd(&cursor[n], 1);
        csr[p] = n;  // self loop
    }
}

// ---------------------------------------------------------------------------
// bf16-MFMA GEMM, BM=BN=64, 4 waves. A loaded DIRECT global->reg (each wave
// owns disjoint rows; LDS-staging A bought nothing). B staged via LDS with
// XOR swizzle byte^=(col&7)<<4 (shared across all 4 waves). LDS = 16 KB.
// ---------------------------------------------------------------------------
template <int ACT, int OUTBF>
__global__ __launch_bounds__(256) void k_gemm_mfma(const float* __restrict__ A,
                                                   const float* __restrict__ B,
                                                   const float* __restrict__ bias,
                                                   void* __restrict__ Cv,
                                                   int M, int Nn, int K) {
    __shared__ unsigned short BsU[64 * 128];
    char* BsB = (char*)BsU;
    const int tid = threadIdx.x;
    const int lane = tid & 63;
    const int wv = tid >> 6;
    const int row0 = blockIdx.y * 64, col0 = blockIdx.x * 64;
    const int r = lane & 15, q = lane >> 4;

    const int arow = row0 + wv * 16 + r;
    const bool rowok = arow < M;
    const float* Ap = A + (size_t)arow * K;

    f32x4 acc[4];
#pragma unroll
    for (int i = 0; i < 4; i++) acc[i] = (f32x4){0.f, 0.f, 0.f, 0.f};

    for (int k0 = 0; k0 < K; k0 += 128) {
        __syncthreads();  // protect Bs from previous iteration's readers
        // stage B chunk transposed: Bs[col][k], swizzled
#pragma unroll
        for (int it = 0; it < 8; it++) {
            int gq = tid + it * 256;       // 0..2047
            int kk = gq >> 4;              // 0..127
            int c4 = (gq & 15) * 4;        // 0,4,..,60
            float4 v = *(const float4*)(B + (size_t)(k0 + kk) * Nn + col0 + c4);
            float vv[4] = {v.x, v.y, v.z, v.w};
#pragma unroll
            for (int c = 0; c < 4; c++) {
                int col = c4 + c;
                int byte = (col * 256 + kk * 2) ^ ((col & 7) << 4);
                *(unsigned short*)(BsB + byte) = f2bf(vv[c]);
            }
        }
        __syncthreads();
#pragma unroll
        for (int ks = 0; ks < 4; ks++) {
            int ka = k0 + ks * 32 + q * 8;
            float4 a0 = make_float4(0.f, 0.f, 0.f, 0.f);
            float4 a1 = make_float4(0.f, 0.f, 0.f, 0.f);
            if (rowok) {
                a0 = *(const float4*)(Ap + ka);
                a1 = *(const float4*)(Ap + ka + 4);
            }
            bf16x8 af;
            af[0] = (short)f2bf(a0.x); af[1] = (short)f2bf(a0.y);
            af[2] = (short)f2bf(a0.z); af[3] = (short)f2bf(a0.w);
            af[4] = (short)f2bf(a1.x); af[5] = (short)f2bf(a1.y);
            af[6] = (short)f2bf(a1.z); af[7] = (short)f2bf(a1.w);
            int kb = (ks * 32 + q * 8) * 2;
#pragma unroll
            for (int nb = 0; nb < 4; nb++) {
                int col = nb * 16 + r;
                bf16x8 bfr = *(bf16x8*)(BsB + ((col * 256 + kb) ^ ((col & 7) << 4)));
                acc[nb] = __builtin_amdgcn_mfma_f32_16x16x32_bf16(af, bfr, acc[nb], 0, 0, 0);
            }
        }
    }
    // epilogue: D mapping col=lane&15, row=(lane>>4)*4+reg
#pragma unroll
    for (int nb = 0; nb < 4; nb++) {
        int col = col0 + nb * 16 + r;
#pragma unroll
        for (int j = 0; j < 4; j++) {
            int row = row0 + wv * 16 + q * 4 + j;
            if (row < M) {
                float v = acc[nb][j];
                if (ACT) { v += bias[col]; v = eluf(v); }
                if (OUTBF) ((unsigned short*)Cv)[(size_t)row * Nn + col] = f2bf(v);
                else       ((float*)Cv)[(size_t)row * Nn + col] = v;
            }
        }
    }
}

// ---------------------------------------------------------------------------
// alpha_s[n,h] = sum_c xl[n,h,c]*att_src[h,c] (xl bf16). One wave/node.
// ---------------------------------------------------------------------------
__global__ __launch_bounds__(256) void k_alphas(const ushort16* __restrict__ xl,
                                                const float* __restrict__ atts,
                                                const float* __restrict__ attd,
                                                float* __restrict__ as_,
                                                float* __restrict__ ad_) {
    int lane = threadIdx.x & 63;
    int n = blockIdx.x * 4 + (threadIdx.x >> 6);
    if (n >= N_NODES) return;
    int g = lane >> 4;          // 0..3
    int c8 = 8 * (lane & 15);   // channel base
    const uint4* xp = (const uint4*)(xl + (size_t)n * 1024);
    float ss[2], sd[2];
#pragma unroll
    for (int j = 0; j < 2; j++) {
        int head = 4 * j + g;
        uint4 u = xp[j * 64 + lane];
        const float4* ap = (const float4*)(atts + head * 128 + c8);
        const float4* bp = (const float4*)(attd + head * 128 + c8);
        float4 a0 = ap[0], a1 = ap[1];
        float4 b0 = bp[0], b1 = bp[1];
        float x0 = blo(u.x), x1 = bhi(u.x), x2 = blo(u.y), x3 = bhi(u.y);
        float x4 = blo(u.z), x5 = bhi(u.z), x6 = blo(u.w), x7 = bhi(u.w);
        ss[j] = x0 * a0.x + x1 * a0.y + x2 * a0.z + x3 * a0.w +
                x4 * a1.x + x5 * a1.y + x6 * a1.z + x7 * a1.w;
        sd[j] = x0 * b0.x + x1 * b0.y + x2 * b0.z + x3 * b0.w +
                x4 * b1.x + x5 * b1.y + x6 * b1.z + x7 * b1.w;
    }
#pragma unroll
    for (int m = 1; m < 16; m <<= 1) {
#pragma unroll
        for (int j = 0; j < 2; j++) {
            ss[j] += __shfl_xor(ss[j], m);
            sd[j] += __shfl_xor(sd[j], m);
        }
    }
    if ((lane & 15) == 0) {
        as_[n * 8 + g]     = ss[0];
        as_[n * 8 + 4 + g] = ss[1];
        ad_[n * 8 + g]     = sd[0];
        ad_[n * 8 + 4 + g] = sd[1];
    }
}

// ---------------------------------------------------------------------------
// Aggregation, wave-split (round-11 proven): block = 4 waves = 2 nodes x 2.
// ---------------------------------------------------------------------------
__global__ __launch_bounds__(256) void k_aggregate(const int* __restrict__ rowptr,
                                                   const int* __restrict__ csr,
                                                   const float* __restrict__ as_,
                                                   const float* __restrict__ ad_,
                                                   const ushort16* __restrict__ xl,
                                                   const float* __restrict__ hprev,
                                                   const float* __restrict__ bl,
                                                   const float* __restrict__ gam,
                                                   const float* __restrict__ bet,
                                                   float* __restrict__ hnext) {
    __shared__ float cmb[2][64][17];   // [node slot][lane][acc0 x8, acc1 x8, denom]
    int tid = threadIdx.x;
    int lane = tid & 63;
    int wv = tid >> 6;
    int which = wv >> 1;               // node slot in block
    int par = wv & 1;                  // edge parity handled by this wave
    int n = blockIdx.x * 2 + which;    // grid = N/2 exactly
    int h8 = lane & 7;
    int g = lane >> 4;
    float adh = ad_[n * 8 + h8];
    int start = rowptr[n], end = rowptr[n + 1];

    float acc0[8] = {}, acc1[8] = {};
    float denom = 0.f;
    int e = start + par;
    for (; e + 2 < end; e += 4) {      // edges e and e+2 (same parity class)
        int s0 = csr[e], s1 = csr[e + 2];
        float a0 = as_[s0 * 8 + h8];
        float a1 = as_[s1 * 8 + h8];
        const uint4* xp0 = (const uint4*)(xl + (size_t)s0 * 1024);
        const uint4* xp1 = (const uint4*)(xl + (size_t)s1 * 1024);
        uint4 u0a = xp0[lane], u1a = xp0[64 + lane];
        uint4 u0b = xp1[lane], u1b = xp1[64 + lane];
        float ee0 = __expf(lrelu(a0 + adh));
        float ee1 = __expf(lrelu(a1 + adh));
        denom += ee0 + ee1;
        float e0a = __shfl(ee0, g), e1a = __shfl(ee0, 4 + g);
        float e0b = __shfl(ee1, g), e1b = __shfl(ee1, 4 + g);
        acc0[0] += e0a * blo(u0a.x) + e0b * blo(u0b.x);
        acc0[1] += e0a * bhi(u0a.x) + e0b * bhi(u0b.x);
        acc0[2] += e0a * blo(u0a.y) + e0b * blo(u0b.y);
        acc0[3] += e0a * bhi(u0a.y) + e0b * bhi(u0b.y);
        acc0[4] += e0a * blo(u0a.z) + e0b * blo(u0b.z);
        acc0[5] += e0a * bhi(u0a.z) + e0b * bhi(u0b.z);
        acc0[6] += e0a * blo(u0a.w) + e0b * blo(u0b.w);
        acc0[7] += e0a * bhi(u0a.w) + e0b * bhi(u0b.w);
        acc1[0] += e1a * blo(u1a.x) + e1b * blo(u1b.x);
        acc1[1] += e1a * bhi(u1a.x) + e1b * bhi(u1b.x);
        acc1[2] += e1a * blo(u1a.y) + e1b * blo(u1b.y);
        acc1[3] += e1a * bhi(u1a.y) + e1b * bhi(u1b.y);
        acc1[4] += e1a * blo(u1a.z) + e1b * blo(u1b.z);
        acc1[5] += e1a * bhi(u1a.z) + e1b * bhi(u1b.z);
        acc1[6] += e1a * blo(u1a.w) + e1b * blo(u1b.w);
        acc1[7] += e1a * bhi(u1a.w) + e1b * bhi(u1b.w);
    }
    for (; e < end; e += 2) {          // parity-class tail
        int s0 = csr[e];
        float a0 = as_[s0 * 8 + h8];
        const uint4* xp0 = (const uint4*)(xl + (size_t)s0 * 1024);
        uint4 u0a = xp0[lane], u1a = xp0[64 + lane];
        float ee0 = __expf(lrelu(a0 + adh));
        denom += ee0;
        float e0a = __shfl(ee0, g), e1a = __shfl(ee0, 4 + g);
        acc0[0] += e0a * blo(u0a.x); acc0[1] += e0a * bhi(u0a.x);
        acc0[2] += e0a * blo(u0a.y); acc0[3] += e0a * bhi(u0a.y);
        acc0[4] += e0a * blo(u0a.z); acc0[5] += e0a * bhi(u0a.z);
        acc0[6] += e0a * blo(u0a.w); acc0[7] += e0a * bhi(u0a.w);
        acc1[0] += e1a * blo(u1a.x); acc1[1] += e1a * bhi(u1a.x);
        acc1[2] += e1a * blo(u1a.y); acc1[3] += e1a * bhi(u1a.y);
        acc1[4] += e1a * blo(u1a.z); acc1[5] += e1a * bhi(u1a.z);
        acc1[6] += e1a * blo(u1a.w); acc1[7] += e1a * bhi(u1a.w);
    }

    if (par == 1) {                    // secondary wave publishes partials
#pragma unroll
        for (int i = 0; i < 8; i++) {
            cmb[which][lane][i]     = acc0[i];
            cmb[which][lane][8 + i] = acc1[i];
        }
        cmb[which][lane][16] = denom;
    }
    __syncthreads();                   // uniform: every wave passes exactly once
    if (par == 1) return;
#pragma unroll
    for (int i = 0; i < 8; i++) {
        acc0[i] += cmb[which][lane][i];
        acc1[i] += cmb[which][lane][8 + i];
    }
    denom += cmb[which][lane][16];

    float d0 = __shfl(denom, g);
    float d1 = __shfl(denom, 4 + g);
    float r0 = 1.f / (d0 + 1e-16f);
    float r1 = 1.f / (d1 + 1e-16f);
    float sum[8];
#pragma unroll
    for (int i = 0; i < 8; i++) sum[i] = acc0[i] * r0 + acc1[i] * r1;
#pragma unroll
    for (int i = 0; i < 8; i++) {
        sum[i] += __shfl_xor(sum[i], 16);
        sum[i] += __shfl_xor(sum[i], 32);
    }

    if (lane < 16) {
        int c = 8 * lane;
        float o[8];
#pragma unroll
        for (int t = 0; t < 8; t++) {
            float m = sum[t] * 0.125f + bl[c + t];              // mean heads + bias
            float gg = gam[c + t] * (m * BN_INV) + bet[c + t];  // BN eval
            float z = 0.9f * gg + 0.1f * hprev[(size_t)n * 128 + c + t];
            o[t] = eluf(z);
        }
        *(float4*)(hnext + (size_t)n * 128 + c)     = make_float4(o[0], o[1], o[2], o[3]);
        *(float4*)(hnext + (size_t)n * 128 + c + 4) = make_float4(o[4], o[5], o[6], o[7]);
    }
}

// ---------------------------------------------------------------------------
// Classifier head: out = elu(h@W1+b1) @ W2 + b2, one wave per node.
// ---------------------------------------------------------------------------
__global__ __launch_bounds__(256) void k_classifier(const float* __restrict__ h,
                                                    const float* __restrict__ W1,
                                                    const float* __restrict__ b1,
                                                    const float* __restrict__ W2,
                                                    const float* __restrict__ b2,
                                                    float* __restrict__ out) {
    __shared__ float sW1[128 * 64];
    __shared__ float sW2[128];
    __shared__ float sb1[64];
    __shared__ float sb2[2];
    for (int i = threadIdx.x; i < 2048; i += 256)
        *(float4*)&sW1[i * 4] = *(const float4*)(W1 + i * 4);
    if (threadIdx.x < 64) sb1[threadIdx.x] = b1[threadIdx.x];
    if (threadIdx.x < 128) sW2[threadIdx.x] = W2[threadIdx.x];
    if (threadIdx.x < 2) sb2[threadIdx.x] = b2[threadIdx.x];
    __syncthreads();
    int lane = threadIdx.x & 63;
    int n = blockIdx.x * 4 + (threadIdx.x >> 6);
    if (n >= N_NODES) return;
    float h0 = h[(size_t)n * 128 + lane];
    float h1 = h[(size_t)n * 128 + 64 + lane];
    float acc = sb1[lane];
#pragma unroll
    for (int c = 0; c < 64; c++) acc += __shfl(h0, c) * sW1[c * 64 + lane];
#pragma unroll
    for (int c = 0; c < 64; c++) acc += __shfl(h1, c) * sW1[(64 + c) * 64 + lane];
    acc = eluf(acc);
    float p0 = acc * sW2[lane * 2 + 0];
    float p1 = acc * sW2[lane * 2 + 1];
#pragma unroll
    for (int m = 1; m < 64; m <<= 1) {
        p0 += __shfl_xor(p0, m);
        p1 += __shfl_xor(p1, m);
    }
    if (lane == 0) {
        out[(size_t)n * 2 + 0] = p0 + sb2[0];
        out[(size_t)n * 2 + 1] = p1 + sb2[1];
    }
}

// ---------------------------------------------------------------------------
extern "C" void kernel_launch(void* const* d_in, const int* in_sizes, int n_in,
                              void* d_out, int out_size, void* d_ws, size_t ws_size,
                              hipStream_t stream) {
    const float* x       = (const float*)d_in[0];
    const int* ei        = (const int*)d_in[1];   // int32 per harness convention
    const float* Wp      = (const float*)d_in[2];
    const float* bp      = (const float*)d_in[3];
    const float* Wl      = (const float*)d_in[4];
    const float* atts    = (const float*)d_in[5];
    const float* attd    = (const float*)d_in[6];
    const float* bl      = (const float*)d_in[7];
    const float* gam     = (const float*)d_in[8];
    const float* bet     = (const float*)d_in[9];
    const float* W1      = (const float*)d_in[10];
    const float* b1      = (const float*)d_in[11];
    const float* W2      = (const float*)d_in[12];
    const float* b2      = (const float*)d_in[13];
    float* out = (float*)d_out;

    char* w = (char*)d_ws;
    auto carve = [&](size_t bytes) -> void* {
        void* p = (void*)w;
        w += (bytes + 255) & ~(size_t)255;
        return p;
    };
    int* deg        = (int*)carve((size_t)N_NODES * 4);
    int* rowptr     = (int*)carve((size_t)(N_NODES + 1) * 4);
    int* cursor     = (int*)carve((size_t)N_NODES * 4);
    int* csr        = (int*)carve((size_t)(N_EDGES + N_NODES) * 4);
    float* as_      = (float*)carve((size_t)N_NODES * 8 * 4);
    float* ad_      = (float*)carve((size_t)N_NODES * 8 * 4);
    ushort16* xl    = (ushort16*)carve((size_t)N_NODES * 1024 * 2);  // bf16
    float* hA       = (float*)carve((size_t)N_NODES * 128 * 4);
    float* hB       = (float*)carve((size_t)N_NODES * 128 * 4);

    hipMemsetAsync(deg, 0, (size_t)N_NODES * 4, stream);
    k_deg<<<(N_EDGES + 255) / 256, 256, 0, stream>>>(ei, deg);
    k_scan<<<1, 1024, 0, stream>>>(deg, rowptr, cursor);
    k_scatter<<<(N_EDGES + N_NODES + 255) / 256, 256, 0, stream>>>(ei, cursor, csr);

    // h = elu(x @ Wp + bp)  (bf16-MFMA, fp32 out)
    k_gemm_mfma<1, 0><<<dim3(2, 157), 256, 0, stream>>>(x, Wp, bp, hA, N_NODES, 128, 512);

    float* hc = hA;
    float* hn = hB;
    for (int l = 0; l < NLAYER; l++) {
        // xl = hc @ Wl[l]  (bf16-MFMA, bf16 out)
        k_gemm_mfma<0, 1><<<dim3(16, 157), 256, 0, stream>>>(hc, Wl + (size_t)l * 128 * 1024,
                                                             nullptr, xl, N_NODES, 1024, 128);
        k_alphas<<<2500, 256, 0, stream>>>(xl, atts + l * 1024, attd + l * 1024, as_, ad_);
        k_aggregate<<<5000, 256, 0, stream>>>(rowptr, csr, as_, ad_, xl, hc, bl + l * 128,
                                              gam + l * 128, bet + l * 128, hn);
        float* tmp = hc; hc = hn; hn = tmp;
    }
    k_classifier<<<2500, 256, 0, stream>>>(hc, W1, b1, W2, b2, out);
}